// Round 1
// baseline (429.826 us; speedup 1.0000x reference)
//
#include <hip/hip_runtime.h>

#define SEQ   1024
#define NT    128     // num tags
#define NBATCH 256
#define SPLIT 4
#define THREADS (NT * SPLIT)   // 512

// One block per batch element. Threads laid out tid = j*4 + q:
//   j in [0,128): output tag owned by this 4-thread group
//   q in [0,4):  which 32-wide slice of the i-sum this thread computes
// Scaled forward algorithm: gamma kept in linear domain, rescaled by
// c = gamma[0] each step, logC accumulates log(c).
__global__ __launch_bounds__(THREADS, 2) void crf_fwd(
    const float* __restrict__ emissions,   // [B, SEQ, NT]
    const float* __restrict__ transitions, // [NT, NT]
    const int*   __restrict__ tags,        // [B, SEQ]
    const float* __restrict__ mask,        // [B, SEQ]
    float* __restrict__ out)               // [1]
{
    const int b    = blockIdx.x;
    const int tid  = threadIdx.x;
    const int j    = tid >> 2;    // 0..127
    const int q    = tid & 3;     // 0..3
    const int lane = tid & 63;

    // gamma double buffer: 4 quarters of 32 floats, each quarter padded to
    // 36 words so quarter q starts at bank 4q -> the 4 simultaneous b128
    // reads (one per q) hit disjoint banks. 16B alignment kept (36*4=144B).
    __shared__ __align__(16) float g_lds[2][144];
    __shared__ float c_lds[2];
    __shared__ float red[THREADS / 64];

    const float* emb = emissions + (size_t)b * SEQ * NT;
    const float* mkb = mask      + (size_t)b * SEQ;

    // expT column j, rows q*32 .. q*32+31, in registers (statically indexed)
    float colT[32];
#pragma unroll
    for (int k = 0; k < 32; ++k) {
        colT[k] = __expf(transitions[(q * 32 + k) * NT + j]);
    }

    // init: gamma_0 = exp(emissions[b,0,:]), scale c_0 = 1
    if (q == 0) {
        g_lds[0][(j >> 5) * 36 + (j & 31)] = __expf(emb[j]);
    }
    if (tid == 0) { c_lds[0] = 1.0f; }
    __syncthreads();

    float logC = 0.0f;
    int   p    = 0;   // parity: current gamma lives in g_lds[p]

    // software-pipelined emission/mask loads, 4 steps per group:
    // lane (j,q) loads t0+q, values distributed per-step via shfl
    float Ecur, Mcur;
    {
        int t = 1 + q;                 // first group: t = 1..4, all < SEQ
        Ecur = emb[t * NT + j];
        Mcur = mkb[t];
    }

    for (int t0 = 1; t0 < SEQ; t0 += 4) {
        // prefetch next group (clamped)
        int tn = t0 + 4 + q;
        if (tn > SEQ - 1) tn = SEQ - 1;
        float Enext = emb[tn * NT + j];
        float Mnext = mkb[tn];

#pragma unroll
        for (int dq = 0; dq < 4; ++dq) {
            int t = t0 + dq;
            if (t < SEQ) {
                int   src = (lane & 0x3C) | dq;
                float mt  = __shfl(Mcur, src, 64);   // uniform across block
                float et  = __shfl(Ecur, src, 64);

                if (mt != 0.0f) {
                    const float* gp = &g_lds[p][q * 36];
                    float s0 = 0.f, s1 = 0.f, s2 = 0.f, s3 = 0.f;
#pragma unroll
                    for (int c = 0; c < 8; ++c) {
                        float4 g4 = *(const float4*)(gp + c * 4);
                        s0 += g4.x * colT[c * 4 + 0];
                        s1 += g4.y * colT[c * 4 + 1];
                        s2 += g4.z * colT[c * 4 + 2];
                        s3 += g4.w * colT[c * 4 + 3];
                    }
                    float s = (s0 + s1) + (s2 + s3);
                    // combine the 4 i-slices (partners are adjacent lanes)
                    s += __shfl_xor(s, 1, 64);
                    s += __shfl_xor(s, 2, 64);

                    float cprev = c_lds[p];
                    float rc    = __builtin_amdgcn_rcpf(cprev);
                    float gamma = s * rc * __expf(et);
                    logC += __logf(cprev);

                    if (q == 0)
                        g_lds[p ^ 1][(j >> 5) * 36 + (j & 31)] = gamma;
                    if (tid == 0)
                        c_lds[p ^ 1] = gamma;   // tid==0 <=> j==0
                    p ^= 1;
                }
                __syncthreads();
            }
        }
        Ecur = Enext; Mcur = Mnext;
    }

    // logZ = log(sum_j gamma[j]) + logC
    float v = 0.0f;
    if (tid < NT) v = g_lds[p][(tid >> 5) * 36 + (tid & 31)];
#pragma unroll
    for (int o = 32; o > 0; o >>= 1) v += __shfl_down(v, o, 64);
    if (lane == 0) red[tid >> 6] = v;
    __syncthreads();
    float sumG = 0.0f;
    if (tid == 0) {
#pragma unroll
        for (int k = 0; k < THREADS / 64; ++k) sumG += red[k];
    }
    __syncthreads();   // protect red[] before reuse

    // score_b = sum_t emissions[b,t,tag_t]*mask_t
    //         + sum_{t>=1} T[tag_{t-1}, tag_t]*mask_t
    const int* tgb = tags + (size_t)b * SEQ;
    float sc = 0.0f;
    for (int t = tid; t < SEQ; t += THREADS) {
        int   tg = tgb[t];
        float mt = mkb[t];
        sc += emb[t * NT + tg] * mt;
        if (t >= 1) {
            int tgp = tgb[t - 1];
            sc += transitions[tgp * NT + tg] * mt;
        }
    }
#pragma unroll
    for (int o = 32; o > 0; o >>= 1) sc += __shfl_down(sc, o, 64);
    if (lane == 0) red[tid >> 6] = sc;
    __syncthreads();

    if (tid == 0) {
        float score = 0.0f;
#pragma unroll
        for (int k = 0; k < THREADS / 64; ++k) score += red[k];
        float logZ = __logf(sumG) + logC;
        atomicAdd(out, (logZ - score) * (1.0f / NBATCH));
    }
}

extern "C" void kernel_launch(void* const* d_in, const int* in_sizes, int n_in,
                              void* d_out, int out_size, void* d_ws, size_t ws_size,
                              hipStream_t stream) {
    const float* emissions   = (const float*)d_in[0];
    const float* transitions = (const float*)d_in[1];
    const int*   tags        = (const int*)d_in[2];
    const float* mask        = (const float*)d_in[3];
    float*       out         = (float*)d_out;

    hipMemsetAsync(out, 0, sizeof(float), stream);
    crf_fwd<<<NBATCH, THREADS, 0, stream>>>(emissions, transitions, tags, mask, out);
}